// Round 1
// baseline (3251.368 us; speedup 1.0000x reference)
//
#include <hip/hip_runtime.h>

// BiLSTM: B=512, T=1024, D_IN=64, H=50, 2 layers bidirectional, FC on h[:, -1].
// Phase A: layer-0 fwd+bwd scans (1024 blocks, one per (row,dir)), writes h_l0 (B,T,100) to ws.
// Phase B: layer-1 fwd scan (512 blocks), writes final h (cols 0..49 of h1cat).
// Phase C: layer-1 bwd = single LSTM step at t=T-1 (h0=0 -> no Whh term), cols 50..99.
// Phase D: FC dot(h1cat[b], fc_w) + fc_b -> out (512 floats).

#define BATCH 512
#define TT    1024
#define DIN   64
#define DIN1  100
#define HH    50
#define GG    200   // 4*H

__device__ __forceinline__ float sigf(float x)     { return 1.f / (1.f + __expf(-x)); }
__device__ __forceinline__ float tanhfast(float x) { return 1.f - 2.f / (__expf(2.f * x) + 1.f); }

// ---------------- Layer 0: one block per (row, dir). 256 threads. ----------------
// Thread u<200 owns gate-row u: Wih row (64) + Whh row (50) in REGISTERS (read once,
// used 1024x -> avoids LDS weight streaming which would be 3x over the FMA budget).
// x prefetched 2 steps ahead (even/odd reg pipeline) into double-buffered LDS.
__global__ __launch_bounds__(256) void scan_l0(
    const float* __restrict__ x,
    const float* __restrict__ Wih_f, const float* __restrict__ Whh_f,
    const float* __restrict__ bih_f, const float* __restrict__ bhh_f,
    const float* __restrict__ Wih_b, const float* __restrict__ Whh_b,
    const float* __restrict__ bih_b, const float* __restrict__ bhh_b,
    float* __restrict__ hout)           // (B, T, 100)
{
    const int bid = blockIdx.x;
    const int dir = bid & 1;
    const int row = bid >> 1;
    const int tid = threadIdx.x;

    const float* Wih  = dir ? Wih_b : Wih_f;
    const float* Whh  = dir ? Whh_b : Whh_f;
    const float* bihp = dir ? bih_b : bih_f;
    const float* bhhp = dir ? bhh_b : bhh_f;

    __shared__ float x_s[2][DIN];
    __shared__ float h_sm[2][HH];
    __shared__ float gbuf[GG];

    float wih[DIN], whh[HH];
    float bias = 0.f;
    if (tid < GG) {
#pragma unroll
        for (int k = 0; k < DIN; ++k) wih[k] = Wih[tid * DIN + k];
#pragma unroll
        for (int k = 0; k < HH; ++k) whh[k] = Whh[tid * HH + k];
        bias = bihp[tid] + bhhp[tid];
    }

    const float* xrow = x + (size_t)row * TT * DIN;
    float* hrow = hout + (size_t)row * TT * 100 + dir * HH;

    float c = 0.f;
    float xE = 0.f, xO = 0.f;
    if (tid < HH) h_sm[0][tid] = 0.f;
    if (tid < DIN) {
        const int t0 = dir ? (TT - 1) : 0;
        const int t1 = dir ? (TT - 2) : 1;
        const int t2 = dir ? (TT - 3) : 2;
        x_s[0][tid] = xrow[t0 * DIN + tid];
        xE = xrow[t1 * DIN + tid];   // x for step 1 (written to LDS at end of step 0)
        xO = xrow[t2 * DIN + tid];   // x for step 2 (written at end of step 1)
    }
    __syncthreads();

    for (int t = 0; t < TT; t += 2) {
        // ---- even step t: read x_s[0], h_sm[0]; write h_sm[1] ----
        if (tid < GG) {
            float acc = bias;
#pragma unroll
            for (int k = 0; k < DIN; ++k) acc += x_s[0][k] * wih[k];
#pragma unroll
            for (int k = 0; k < HH; ++k) acc += h_sm[0][k] * whh[k];
            gbuf[tid] = acc;
        }
        __syncthreads();
        if (tid < HH) {
            float iv = sigf(gbuf[tid]);
            float fv = sigf(gbuf[HH + tid]);
            float gv = tanhfast(gbuf[2 * HH + tid]);
            float ov = sigf(gbuf[3 * HH + tid]);
            c = fv * c + iv * gv;
            float h = ov * tanhfast(c);
            h_sm[1][tid] = h;
            const int tw = dir ? (TT - 1 - t) : t;
            hrow[(size_t)tw * 100 + tid] = h;
        }
        if (tid < DIN) {
            x_s[1][tid] = xE;                       // x for step t+1
            int s = t + 3; if (s > TT - 1) s = TT - 1;
            const int ts = dir ? (TT - 1 - s) : s;
            xE = xrow[ts * DIN + tid];              // prefetch x for step t+3
        }
        __syncthreads();

        // ---- odd step t+1: read x_s[1], h_sm[1]; write h_sm[0] ----
        if (tid < GG) {
            float acc = bias;
#pragma unroll
            for (int k = 0; k < DIN; ++k) acc += x_s[1][k] * wih[k];
#pragma unroll
            for (int k = 0; k < HH; ++k) acc += h_sm[1][k] * whh[k];
            gbuf[tid] = acc;
        }
        __syncthreads();
        if (tid < HH) {
            float iv = sigf(gbuf[tid]);
            float fv = sigf(gbuf[HH + tid]);
            float gv = tanhfast(gbuf[2 * HH + tid]);
            float ov = sigf(gbuf[3 * HH + tid]);
            c = fv * c + iv * gv;
            float h = ov * tanhfast(c);
            h_sm[0][tid] = h;
            const int tw = dir ? (TT - 2 - t) : (t + 1);
            hrow[(size_t)tw * 100 + tid] = h;
        }
        if (tid < DIN) {
            x_s[0][tid] = xO;                       // x for step t+2
            int s = t + 4; if (s > TT - 1) s = TT - 1;
            const int ts = dir ? (TT - 1 - s) : s;
            xO = xrow[ts * DIN + tid];              // prefetch x for step t+4
        }
        __syncthreads();
    }
}

// ---------------- Layer 1 forward: one block per row. Only final h is needed. -----
__global__ __launch_bounds__(256) void scan_l1f(
    const float* __restrict__ hin,   // (B, T, 100) from layer 0
    const float* __restrict__ Wih, const float* __restrict__ Whh,
    const float* __restrict__ bih, const float* __restrict__ bhh,
    float* __restrict__ h1cat)       // (B, 100): we write cols 0..49
{
    const int row = blockIdx.x;
    const int tid = threadIdx.x;

    __shared__ float x_s[2][DIN1];
    __shared__ float h_sm[2][HH];
    __shared__ float gbuf[GG];

    float wih[DIN1], whh[HH];
    float bias = 0.f;
    if (tid < GG) {
#pragma unroll
        for (int k = 0; k < DIN1; ++k) wih[k] = Wih[tid * DIN1 + k];
#pragma unroll
        for (int k = 0; k < HH; ++k) whh[k] = Whh[tid * HH + k];
        bias = bih[tid] + bhh[tid];
    }

    const float* xrow = hin + (size_t)row * TT * DIN1;

    float c = 0.f, xE = 0.f, xO = 0.f;
    if (tid < HH) h_sm[0][tid] = 0.f;
    if (tid < DIN1) {
        x_s[0][tid] = xrow[0 * DIN1 + tid];
        xE = xrow[1 * DIN1 + tid];
        xO = xrow[2 * DIN1 + tid];
    }
    __syncthreads();

    for (int t = 0; t < TT; t += 2) {
        // even
        if (tid < GG) {
            float acc = bias;
#pragma unroll
            for (int k = 0; k < DIN1; ++k) acc += x_s[0][k] * wih[k];
#pragma unroll
            for (int k = 0; k < HH; ++k) acc += h_sm[0][k] * whh[k];
            gbuf[tid] = acc;
        }
        __syncthreads();
        if (tid < HH) {
            float iv = sigf(gbuf[tid]);
            float fv = sigf(gbuf[HH + tid]);
            float gv = tanhfast(gbuf[2 * HH + tid]);
            float ov = sigf(gbuf[3 * HH + tid]);
            c = fv * c + iv * gv;
            float h = ov * tanhfast(c);
            h_sm[1][tid] = h;
        }
        if (tid < DIN1) {
            x_s[1][tid] = xE;
            int s = t + 3; if (s > TT - 1) s = TT - 1;
            xE = xrow[(size_t)s * DIN1 + tid];
        }
        __syncthreads();

        // odd
        if (tid < GG) {
            float acc = bias;
#pragma unroll
            for (int k = 0; k < DIN1; ++k) acc += x_s[1][k] * wih[k];
#pragma unroll
            for (int k = 0; k < HH; ++k) acc += h_sm[1][k] * whh[k];
            gbuf[tid] = acc;
        }
        __syncthreads();
        if (tid < HH) {
            float iv = sigf(gbuf[tid]);
            float fv = sigf(gbuf[HH + tid]);
            float gv = tanhfast(gbuf[2 * HH + tid]);
            float ov = sigf(gbuf[3 * HH + tid]);
            c = fv * c + iv * gv;
            float h = ov * tanhfast(c);
            h_sm[0][tid] = h;
            if (t + 1 == TT - 1) h1cat[row * 100 + tid] = h;  // only last step needed
        }
        if (tid < DIN1) {
            x_s[0][tid] = xO;
            int s = t + 4; if (s > TT - 1) s = TT - 1;
            xO = xrow[(size_t)s * DIN1 + tid];
        }
        __syncthreads();
    }
}

// ------------- Layer 1 backward at t=T-1: single step, h0=c0=0 -> no Whh term. ----
__global__ __launch_bounds__(256) void l1b_step(
    const float* __restrict__ hl0,
    const float* __restrict__ Wih,
    const float* __restrict__ bih, const float* __restrict__ bhh,
    float* __restrict__ h1cat)       // cols 50..99
{
    const int row = blockIdx.x;
    const int tid = threadIdx.x;
    __shared__ float in_s[DIN1];
    __shared__ float gbuf[GG];

    const float* inp = hl0 + ((size_t)row * TT + (TT - 1)) * 100;
    if (tid < DIN1) in_s[tid] = inp[tid];
    __syncthreads();

    if (tid < GG) {
        float acc = bih[tid] + bhh[tid];
#pragma unroll
        for (int k = 0; k < DIN1; ++k) acc += in_s[k] * Wih[tid * DIN1 + k];
        gbuf[tid] = acc;
    }
    __syncthreads();
    if (tid < HH) {
        float iv = sigf(gbuf[tid]);
        // f gate multiplies c0 = 0 -> skip
        float gv = tanhfast(gbuf[2 * HH + tid]);
        float ov = sigf(gbuf[3 * HH + tid]);
        float cc = iv * gv;
        h1cat[row * 100 + HH + tid] = ov * tanhfast(cc);
    }
}

// ---------------- FC: out[b] = dot(h1cat[b], fc_w) + fc_b ----------------
__global__ void fc_out(const float* __restrict__ h1cat,
                       const float* __restrict__ fcw, const float* __restrict__ fcb,
                       float* __restrict__ out)
{
    const int b = blockIdx.x * blockDim.x + threadIdx.x;
    if (b < BATCH) {
        float acc = fcb[0];
#pragma unroll 4
        for (int k = 0; k < DIN1; ++k) acc += h1cat[b * 100 + k] * fcw[k];
        out[b] = acc;
    }
}

extern "C" void kernel_launch(void* const* d_in, const int* in_sizes, int n_in,
                              void* d_out, int out_size, void* d_ws, size_t ws_size,
                              hipStream_t stream) {
    const float* x        = (const float*)d_in[0];
    const float* Wih_l0f  = (const float*)d_in[1];
    const float* Whh_l0f  = (const float*)d_in[2];
    const float* bih_l0f  = (const float*)d_in[3];
    const float* bhh_l0f  = (const float*)d_in[4];
    const float* Wih_l0b  = (const float*)d_in[5];
    const float* Whh_l0b  = (const float*)d_in[6];
    const float* bih_l0b  = (const float*)d_in[7];
    const float* bhh_l0b  = (const float*)d_in[8];
    const float* Wih_l1f  = (const float*)d_in[9];
    const float* Whh_l1f  = (const float*)d_in[10];
    const float* bih_l1f  = (const float*)d_in[11];
    const float* bhh_l1f  = (const float*)d_in[12];
    const float* Wih_l1b  = (const float*)d_in[13];
    /* Whh_l1b d_in[14] unused: h0=0 for the single backward step at t=T-1 */
    const float* bih_l1b  = (const float*)d_in[15];
    const float* bhh_l1b  = (const float*)d_in[16];
    const float* fc_w     = (const float*)d_in[17];
    const float* fc_b     = (const float*)d_in[18];

    float* hl0   = (float*)d_ws;                              // (B, T, 100) = 209.7 MB
    float* h1cat = hl0 + (size_t)BATCH * TT * 100;            // (B, 100)

    scan_l0<<<dim3(2 * BATCH), dim3(256), 0, stream>>>(
        x, Wih_l0f, Whh_l0f, bih_l0f, bhh_l0f,
           Wih_l0b, Whh_l0b, bih_l0b, bhh_l0b, hl0);
    scan_l1f<<<dim3(BATCH), dim3(256), 0, stream>>>(
        hl0, Wih_l1f, Whh_l1f, bih_l1f, bhh_l1f, h1cat);
    l1b_step<<<dim3(BATCH), dim3(256), 0, stream>>>(
        hl0, Wih_l1b, bih_l1b, bhh_l1b, h1cat);
    fc_out<<<dim3(2), dim3(256), 0, stream>>>(h1cat, fc_w, fc_b, (float*)d_out);
}